// Round 7
// baseline (50.610 us; speedup 1.0000x reference)
//
#include <hip/hip_runtime.h>

#define NB 10   // labels 1..10
#define BATCH 8
#define EPSF 1e-6f

constexpr int ELEMS_PER_BATCH = 128 * 128 * 128;        // 2,097,152
constexpr int VEC_PER_BATCH   = ELEMS_PER_BATCH / 4;    // 524,288 float4
constexpr int THREADS         = 256;
constexpr int VPT             = 8;                      // float4 loads per thread per slice
constexpr int SLICE_VEC       = THREADS * VPT;          // 2048 float4 per slice
constexpr int BLOCKS_PER_BATCH = 64;
constexpr int SLICES_PER_BLOCK = VEC_PER_BATCH / (SLICE_VEC * BLOCKS_PER_BATCH); // 4
constexpr int GRID            = BLOCKS_PER_BATCH * BATCH;   // 512 = exactly 2 blocks/CU

// ws: one 32-float record per block: [0..9]=I, [10..19]=X, [20..29]=T, [30]=mask(uint)
// every slot written unconditionally every call -> no zeroing needed.
constexpr int REC = 32;

// waves_per_eu(2,2): pin occupancy to 2 waves/EU (8 waves/CU) so the register
// allocator has a 256-VGPR budget and the scheduler has NO incentive to sink
// the hoisted loads to shrink pressure. ILP replaces TLP for latency hiding.
__global__ __launch_bounds__(THREADS)
__attribute__((amdgpu_waves_per_eu(2, 2)))
void dice_partial(const float* __restrict__ x,
                  const float* __restrict__ t,
                  const int*   __restrict__ s,
                  float* __restrict__ ws)
{
    const int tid   = threadIdx.x;
    const int batch = blockIdx.x >> 6;          // 64 blocks per batch
    const int sub   = blockIdx.x & 63;

    float aI[NB], aX[NB], aT[NB];
#pragma unroll
    for (int k = 0; k < NB; ++k) { aI[k] = 0.f; aX[k] = 0.f; aT[k] = 0.f; }
    unsigned bits = 0;   // bit v set <=> label value v seen

#define DO_ELEM(xe, te, se)                                     \
    do {                                                        \
        const float _x = (xe), _t = (te);                       \
        const int   _s = (se);                                  \
        const float _p = _x * _t;                               \
        bits |= (1u << _s);                                     \
        _Pragma("unroll")                                       \
        for (int k = 0; k < NB; ++k) {                          \
            const float m = (_s == k + 1) ? 1.0f : 0.0f;        \
            aI[k] = fmaf(m, _p, aI[k]);                         \
            aX[k] = fmaf(m, _x, aX[k]);                         \
            aT[k] = fmaf(m, _t, aT[k]);                         \
        }                                                       \
    } while (0)

#pragma unroll 1   // keep one slice's register footprint; TLP covers cross-slice
    for (int j = 0; j < SLICES_PER_BLOCK; ++j) {
        const long long base = (long long)batch * VEC_PER_BATCH
                             + (long long)(sub + BLOCKS_PER_BATCH * j) * SLICE_VEC;
        const float4* x4 = reinterpret_cast<const float4*>(x) + base;
        const float4* t4 = reinterpret_cast<const float4*>(t) + base;
        const int4*   s4 = reinterpret_cast<const int4*>(s)   + base;

        // issue ALL 24 loads (96 VGPRs of destinations, 24 KB in flight per wave)
        float4 xv[VPT], tv[VPT]; int4 sv[VPT];
#pragma unroll
        for (int i = 0; i < VPT; ++i) {
            const int idx = i * THREADS + tid;   // coalesced, 16B/lane
            xv[i] = x4[idx];
            tv[i] = t4[idx];
            sv[i] = s4[idx];
        }
        // compiler fence: loads cannot be sunk past this point -> they all
        // ISSUE before compute; waits at first use become counted vmcnt(N).
        asm volatile("" ::: "memory");

#pragma unroll
        for (int i = 0; i < VPT; ++i) {
            DO_ELEM(xv[i].x, tv[i].x, sv[i].x);
            DO_ELEM(xv[i].y, tv[i].y, sv[i].y);
            DO_ELEM(xv[i].z, tv[i].z, sv[i].z);
            DO_ELEM(xv[i].w, tv[i].w, sv[i].w);
        }
    }
#undef DO_ELEM

    // wave-64 butterfly (once per block)
#pragma unroll
    for (int k = 0; k < NB; ++k) {
#pragma unroll
        for (int off = 32; off > 0; off >>= 1) {
            aI[k] += __shfl_xor(aI[k], off);
            aX[k] += __shfl_xor(aX[k], off);
            aT[k] += __shfl_xor(aT[k], off);
        }
    }
#pragma unroll
    for (int off = 32; off > 0; off >>= 1)
        bits |= (unsigned)__shfl_xor((int)bits, off);

    // cross-wave combine in LDS, then PLAIN stores to this block's private record
    __shared__ float    wsum[4][32];
    __shared__ unsigned wb[4];
    const int wave = tid >> 6, lane = tid & 63;
    if (lane < NB) {
        wsum[wave][lane]          = aI[lane];
        wsum[wave][NB + lane]     = aX[lane];
        wsum[wave][2 * NB + lane] = aT[lane];
    }
    if (lane == 0) wb[wave] = bits;
    __syncthreads();

    if (tid < 3 * NB) {
        const float v = wsum[0][tid] + wsum[1][tid] + wsum[2][tid] + wsum[3][tid];
        ws[blockIdx.x * REC + tid] = v;
    }
    if (tid == 0)
        ((unsigned*)ws)[blockIdx.x * REC + 30] = wb[0] | wb[1] | wb[2] | wb[3];
}

__global__ void dice_final(const float* __restrict__ ws, float* __restrict__ out)
{
    const int tid = threadIdx.x;
    __shared__ float    sAll[BATCH][3 * NB];   // summed I/X/T per batch
    __shared__ unsigned um[THREADS];

    // phase 1: 240 combos (batch, which*10+lab) each sum 64 block records
    if (tid < BATCH * 3 * NB) {
        const int batch = tid / (3 * NB);
        const int idx   = tid % (3 * NB);
        float v = 0.0f;
        for (int j = 0; j < BLOCKS_PER_BATCH; ++j)
            v += ws[(batch * BLOCKS_PER_BATCH + j) * REC + idx];
        sAll[batch][idx] = v;
    }

    // phase 2: OR all presence masks
    unsigned m = 0;
#pragma unroll
    for (int j = 0; j < GRID / THREADS; ++j)
        m |= ((const unsigned*)ws)[(tid * (GRID / THREADS) + j) * REC + 30];
    um[tid] = m;
    __syncthreads();
    for (int st = THREADS / 2; st > 0; st >>= 1) {
        if (tid < st) um[tid] |= um[tid + st];
        __syncthreads();
    }
    const unsigned mask = um[0];   // bit v = label value v present (v=1..10)

    // phase 3: dice per label, then reduce over labels (first wave only)
    if (tid < 64) {
        float lpb = 0.0f, pres = 0.0f;
        if (tid < NB) {
            float sum_loss = 0.0f, valid = 0.0f;
            for (int b = 0; b < BATCH; ++b) {
                const float I = sAll[b][tid];
                const float X = sAll[b][NB + tid];
                const float T = sAll[b][2 * NB + tid];
                const float denom = X + T + 2.0f * EPSF;
                float bl = 1.0f - 2.0f * I / denom;
                if (T == 0.0f) bl = 0.0f; else valid += 1.0f;
                sum_loss += bl;
            }
            lpb  = sum_loss / fmaxf(valid, 1.0f);
            pres = ((mask >> (tid + 1)) & 1u) ? 1.0f : 0.0f;
        }
        float num = pres;
        float ls  = (pres > 0.0f) ? lpb : 0.0f;
#pragma unroll
        for (int off = 32; off > 0; off >>= 1) {
            num += __shfl_down(num, off);
            ls  += __shfl_down(ls,  off);
        }
        if (tid == 0) {
            out[0] = ls / num;
            out[1] = 0.0f;
        }
    }
}

extern "C" void kernel_launch(void* const* d_in, const int* in_sizes, int n_in,
                              void* d_out, int out_size, void* d_ws, size_t ws_size,
                              hipStream_t stream)
{
    const float* x = (const float*)d_in[0];
    const float* t = (const float*)d_in[1];
    const int*   s = (const int*)d_in[2];
    float* out = (float*)d_out;
    float* ws  = (float*)d_ws;

    dice_partial<<<GRID, THREADS, 0, stream>>>(x, t, s, ws);
    dice_final<<<1, THREADS, 0, stream>>>(ws, out);
}

// Round 8
// 45.056 us; speedup vs baseline: 1.1233x; 1.1233x over previous
//
#include <hip/hip_runtime.h>

#define NB 10   // labels 1..10
#define BATCH 8
#define EPSF 1e-6f

constexpr int THREADS        = 256;
constexpr int VEC_PER_BATCH  = (128 * 128 * 128) / 4;   // 524,288 float4 per batch
constexpr int BLOCKS_PER_BATCH = 64;
constexpr int GRID           = BLOCKS_PER_BATCH * BATCH; // 512 = 2 blocks/CU
constexpr int WAVE_VEC       = 2048;                     // float4 per wave (contiguous)
constexpr int STAGES         = WAVE_VEC / 64;            // 32 stages, 64 float4 each
// ws: one 32-float record per block: [0..9]=I,[10..19]=X,[20..29]=T,[30]=mask(uint)
constexpr int REC = 32;

// async global->LDS DMA, 16B per lane: dest = wave-uniform base + lane*16 (linear),
// source = per-lane address. No VGPR destinations -> no spill fight.
__device__ __forceinline__ void dma16(const void* g, void* l) {
    __builtin_amdgcn_global_load_lds(
        (const __attribute__((address_space(1))) void*)g,
        (__attribute__((address_space(3))) void*)l, 16, 0, 0);
}

__global__ __launch_bounds__(THREADS)
void dice_partial(const float* __restrict__ x,
                  const float* __restrict__ t,
                  const int*   __restrict__ s,
                  float* __restrict__ ws)
{
    // per-wave private 4-deep ring buffers: no __syncthreads needed in main loop
    __shared__ float4 lx[4][4][64];   // [wave][buf][lane]
    __shared__ float4 lt[4][4][64];
    __shared__ int4   lsb[4][4][64];

    const int tid  = threadIdx.x;
    const int wave = tid >> 6, lane = tid & 63;
    const int batch = blockIdx.x >> 6;          // 64 blocks per batch
    const int sub   = blockIdx.x & 63;
    const long long chunk = (long long)batch * VEC_PER_BATCH
                          + (long long)(sub * 4 + wave) * WAVE_VEC;

    const float4* gx = (const float4*)x + chunk + lane;
    const float4* gt = (const float4*)t + chunk + lane;
    const int4*   gs = (const int4*)s  + chunk + lane;

    float aI[NB], aX[NB], aT[NB];
#pragma unroll
    for (int k = 0; k < NB; ++k) { aI[k] = 0.f; aX[k] = 0.f; aT[k] = 0.f; }
    unsigned bits = 0;   // bit v set <=> label value v seen

#define DO_ELEM(xe, te, se)                                     \
    do {                                                        \
        const float _x = (xe), _t = (te);                       \
        const int   _s = (se);                                  \
        const float _p = _x * _t;                               \
        bits |= (1u << _s);                                     \
        _Pragma("unroll")                                       \
        for (int k = 0; k < NB; ++k) {                          \
            const float m = (_s == k + 1) ? 1.0f : 0.0f;        \
            aI[k] = fmaf(m, _p, aI[k]);                         \
            aX[k] = fmaf(m, _x, aX[k]);                         \
            aT[k] = fmaf(m, _t, aT[k]);                         \
        }                                                       \
    } while (0)

    // prologue: DMA stages 0..2 (9 outstanding vmcnt events)
#pragma unroll
    for (int i = 0; i < 3; ++i) {
        dma16(gx + i * 64, &lx[wave][i][0]);
        dma16(gt + i * 64, &lt[wave][i][0]);
        dma16(gs + i * 64, &lsb[wave][i][0]);
    }
    const float4* px = gx + 3 * 64;   // prefetch pointers
    const float4* pt = gt + 3 * 64;
    const int4*   ps = gs + 3 * 64;

#pragma unroll 1
    for (int i = 0; i < STAGES; ++i) {
        // counted wait: stage i retired; stages i+1,i+2 (6 DMAs) may stay in flight
        if (i <= STAGES - 3)      asm volatile("s_waitcnt vmcnt(6)" ::: "memory");
        else if (i == STAGES - 2) asm volatile("s_waitcnt vmcnt(3)" ::: "memory");
        else                      asm volatile("s_waitcnt vmcnt(0)" ::: "memory");
        __builtin_amdgcn_sched_barrier(0);

        if (i < STAGES - 3) {     // issue stage i+3 into the freed buffer
            const int nb = (i + 3) & 3;
            dma16(px, &lx[wave][nb][0]);
            dma16(pt, &lt[wave][nb][0]);
            dma16(ps, &lsb[wave][nb][0]);
            px += 64; pt += 64; ps += 64;
        }

        const int b = i & 3;      // consume stage i (3x ds_read_b128)
        const float4 xv = lx[wave][b][lane];
        const float4 tv = lt[wave][b][lane];
        const int4   sv = lsb[wave][b][lane];
        DO_ELEM(xv.x, tv.x, sv.x);
        DO_ELEM(xv.y, tv.y, sv.y);
        DO_ELEM(xv.z, tv.z, sv.z);
        DO_ELEM(xv.w, tv.w, sv.w);
    }
#undef DO_ELEM

    // wave-64 butterfly (once per block)
#pragma unroll
    for (int k = 0; k < NB; ++k) {
#pragma unroll
        for (int off = 32; off > 0; off >>= 1) {
            aI[k] += __shfl_xor(aI[k], off);
            aX[k] += __shfl_xor(aX[k], off);
            aT[k] += __shfl_xor(aT[k], off);
        }
    }
#pragma unroll
    for (int off = 32; off > 0; off >>= 1)
        bits |= (unsigned)__shfl_xor((int)bits, off);

    // cross-wave combine in LDS, then plain stores to this block's record
    __shared__ float    wsum[4][32];
    __shared__ unsigned wb[4];
    if (lane < NB) {
        wsum[wave][lane]          = aI[lane];
        wsum[wave][NB + lane]     = aX[lane];
        wsum[wave][2 * NB + lane] = aT[lane];
    }
    if (lane == 0) wb[wave] = bits;
    __syncthreads();

    if (tid < 3 * NB) {
        const float v = wsum[0][tid] + wsum[1][tid] + wsum[2][tid] + wsum[3][tid];
        ws[blockIdx.x * REC + tid] = v;
    }
    if (tid == 0)
        ((unsigned*)ws)[blockIdx.x * REC + 30] = wb[0] | wb[1] | wb[2] | wb[3];
}

__global__ void dice_final(const float* __restrict__ ws, float* __restrict__ out)
{
    const int tid = threadIdx.x;
    __shared__ float    sAll[BATCH][3 * NB];   // summed I/X/T per batch
    __shared__ unsigned um[THREADS];

    // phase 1: 240 combos (batch, which*10+lab) each sum 64 block records
    if (tid < BATCH * 3 * NB) {
        const int batch = tid / (3 * NB);
        const int idx   = tid % (3 * NB);
        float v = 0.0f;
        for (int j = 0; j < BLOCKS_PER_BATCH; ++j)
            v += ws[(batch * BLOCKS_PER_BATCH + j) * REC + idx];
        sAll[batch][idx] = v;
    }

    // phase 2: OR all presence masks
    unsigned m = 0;
#pragma unroll
    for (int j = 0; j < GRID / THREADS; ++j)
        m |= ((const unsigned*)ws)[(tid * (GRID / THREADS) + j) * REC + 30];
    um[tid] = m;
    __syncthreads();
    for (int st = THREADS / 2; st > 0; st >>= 1) {
        if (tid < st) um[tid] |= um[tid + st];
        __syncthreads();
    }
    const unsigned mask = um[0];   // bit v = label value v present (v=1..10)

    // phase 3: dice per label, then reduce over labels (first wave only)
    if (tid < 64) {
        float lpb = 0.0f, pres = 0.0f;
        if (tid < NB) {
            float sum_loss = 0.0f, valid = 0.0f;
            for (int b = 0; b < BATCH; ++b) {
                const float I = sAll[b][tid];
                const float X = sAll[b][NB + tid];
                const float T = sAll[b][2 * NB + tid];
                const float denom = X + T + 2.0f * EPSF;
                float bl = 1.0f - 2.0f * I / denom;
                if (T == 0.0f) bl = 0.0f; else valid += 1.0f;
                sum_loss += bl;
            }
            lpb  = sum_loss / fmaxf(valid, 1.0f);
            pres = ((mask >> (tid + 1)) & 1u) ? 1.0f : 0.0f;
        }
        float num = pres;
        float ls  = (pres > 0.0f) ? lpb : 0.0f;
#pragma unroll
        for (int off = 32; off > 0; off >>= 1) {
            num += __shfl_down(num, off);
            ls  += __shfl_down(ls,  off);
        }
        if (tid == 0) {
            out[0] = ls / num;
            out[1] = 0.0f;
        }
    }
}

extern "C" void kernel_launch(void* const* d_in, const int* in_sizes, int n_in,
                              void* d_out, int out_size, void* d_ws, size_t ws_size,
                              hipStream_t stream)
{
    const float* x = (const float*)d_in[0];
    const float* t = (const float*)d_in[1];
    const int*   s = (const int*)d_in[2];
    float* out = (float*)d_out;
    float* ws  = (float*)d_ws;

    dice_partial<<<GRID, THREADS, 0, stream>>>(x, t, s, ws);
    dice_final<<<1, THREADS, 0, stream>>>(ws, out);
}